// Round 4
// baseline (1072.277 us; speedup 1.0000x reference)
//
#include <hip/hip_runtime.h>
#include <math.h>

// GATGuard: 3-layer GAT, cosine-sim attention (thresh 0.1), L1 row norm,
// exp weights, degree self-loop. fp32. N=50000, E=800000, 128->256->256->16.
//
// R4: phase A restructured to 16-lane "edge engines" (quarter-wave per edge,
// 16 edges concurrently per block, 2-deep software pipeline) to raise
// memory-level parallelism on the random row gathers; 4-level shuffle reduce.

static inline int cdiv(int a, int b){ return (a + b - 1) / b; }

// ---------------- CSR build (from row[]/col[]) ----------------

__global__ void count_kernel(const int* __restrict__ row, int* __restrict__ cnt, int E){
  int e = blockIdx.x * blockDim.x + threadIdx.x;
  if (e < E) atomicAdd(&cnt[row[e]], 1);
}

__global__ void scan_kernel(const int* __restrict__ cnt, int* __restrict__ offs, int n){
  __shared__ int tmp[1024];
  __shared__ int carry_s;
  int tid = threadIdx.x;
  if (tid == 0) carry_s = 0;
  __syncthreads();
  for (int base = 0; base < n; base += 1024){
    int v = (base + tid < n) ? cnt[base + tid] : 0;
    tmp[tid] = v;
    __syncthreads();
    for (int off = 1; off < 1024; off <<= 1){
      int t = (tid >= off) ? tmp[tid - off] : 0;
      __syncthreads();
      tmp[tid] += t;
      __syncthreads();
    }
    if (base + tid < n) offs[base + tid] = carry_s + tmp[tid] - v;  // exclusive
    __syncthreads();
    if (tid == 0) carry_s += tmp[1023];
    __syncthreads();
  }
  if (tid == 0) offs[n] = carry_s;
}

__global__ void initcur_kernel(const int* __restrict__ offs, int* __restrict__ cur, int n){
  int i = blockIdx.x * blockDim.x + threadIdx.x;
  if (i < n) cur[i] = offs[i];
}

__global__ void scatter_kernel(const int* __restrict__ row, const int* __restrict__ col,
                               int* __restrict__ cur, int* __restrict__ ecol, int E){
  int e = blockIdx.x * blockDim.x + threadIdx.x;
  if (e < E){
    int p = atomicAdd(&cur[row[e]], 1);
    ecol[p] = col[e];
  }
}

// ---------------- layer-0 invnorm (x) ----------------

__global__ void invnorm128_kernel(const float* __restrict__ x, float* __restrict__ invn, int N){
  int n = blockIdx.x * 4 + (threadIdx.x >> 6);
  int lane = threadIdx.x & 63;
  if (n >= N) return;
  float2 a = ((const float2*)(x + (size_t)n * 128))[lane];
  float ss = a.x * a.x + a.y * a.y;
  for (int off = 32; off; off >>= 1) ss += __shfl_xor(ss, off);
  if (lane == 0) invn[n] = 1.0f / fmaxf(sqrtf(ss), 1e-12f);
}

// ---------------- fused attention + input-space aggregation ----------------
// D  = feature dim for similarity (x rows); ZD = dim aggregated; out is N x ZD.
template<int D, int ZD>
__global__ void fused_att_agg(const float* __restrict__ x, const float* __restrict__ invn,
                              const int* __restrict__ offs, const int* __restrict__ ecol,
                              float* __restrict__ simcsr, const float* __restrict__ zagg,
                              float* __restrict__ out, int N){
  constexpr int VECS = D / 64;   // float4s per lane, 16 lanes per edge engine
  __shared__ __align__(16) float xs[D];
  __shared__ float wv[256];
  __shared__ int   cv[256];
  __shared__ float red[256];
  __shared__ float rowsum_s;
  __shared__ int   deg_s;
  __shared__ int   cnt2_s;
  __shared__ float inv_s, wself_s;
  const int n = blockIdx.x;
  const int tid = threadIdx.x;
  const int wave = tid >> 6, lane = tid & 63;
  const int sub = lane >> 4, sl = lane & 15;   // edge engine: 16 lanes
  const int eng = wave * 4 + sub;              // 0..15
  if (tid == 0){ rowsum_s = 0.0f; deg_s = 0; cnt2_s = 0; }
  const int s = offs[n], e = offs[n + 1];
  const float inr = invn[n];
  for (int i = tid; i < D; i += 256) xs[i] = x[(size_t)n * D + i];
  __syncthreads();

  // ---- phase A: 16 edge engines, 2-deep pipelined gathers ----
  float4 a[VECS];
  #pragma unroll
  for (int v = 0; v < VECS; v++) a[v] = ((const float4*)xs)[v * 16 + sl];

  int k = s + eng;
  for (; k + 16 < e; k += 32){
    int c0 = ecol[k], c1 = ecol[k + 16];
    const float4* b0p = (const float4*)(x + (size_t)c0 * D);
    const float4* b1p = (const float4*)(x + (size_t)c1 * D);
    float4 b0[VECS], b1[VECS];
    #pragma unroll
    for (int v = 0; v < VECS; v++) b0[v] = b0p[v * 16 + sl];
    #pragma unroll
    for (int v = 0; v < VECS; v++) b1[v] = b1p[v * 16 + sl];
    float d0 = 0.0f, d1 = 0.0f;
    #pragma unroll
    for (int v = 0; v < VECS; v++){
      d0 += a[v].x*b0[v].x + a[v].y*b0[v].y + a[v].z*b0[v].z + a[v].w*b0[v].w;
      d1 += a[v].x*b1[v].x + a[v].y*b1[v].y + a[v].z*b1[v].z + a[v].w*b1[v].w;
    }
    #pragma unroll
    for (int off = 8; off; off >>= 1){ d0 += __shfl_xor(d0, off); d1 += __shfl_xor(d1, off); }
    if (sl == 0){
      d0 *= inr * invn[c0];
      d1 *= inr * invn[c1];
      if (d0 < 0.1f) d0 = 0.0f;
      if (d1 < 0.1f) d1 = 0.0f;
      simcsr[k] = d0; simcsr[k + 16] = d1;
      int dg = (d0 != 0.0f) + (d1 != 0.0f);
      if (dg){ atomicAdd(&rowsum_s, d0 + d1); atomicAdd(&deg_s, dg); }
    }
  }
  for (; k < e; k += 16){
    int c0 = ecol[k];
    const float4* b0p = (const float4*)(x + (size_t)c0 * D);
    float4 b0[VECS];
    #pragma unroll
    for (int v = 0; v < VECS; v++) b0[v] = b0p[v * 16 + sl];
    float d0 = 0.0f;
    #pragma unroll
    for (int v = 0; v < VECS; v++)
      d0 += a[v].x*b0[v].x + a[v].y*b0[v].y + a[v].z*b0[v].z + a[v].w*b0[v].w;
    #pragma unroll
    for (int off = 8; off; off >>= 1) d0 += __shfl_xor(d0, off);
    if (sl == 0){
      d0 *= inr * invn[c0];
      if (d0 < 0.1f) d0 = 0.0f;
      simcsr[k] = d0;
      if (d0 != 0.0f){ atomicAdd(&rowsum_s, d0); atomicAdd(&deg_s, 1); }
    }
  }
  __syncthreads();
  if (tid == 0){
    float rs = rowsum_s;
    inv_s = (rs > 0.0f) ? 1.0f / rs : 0.0f;
    wself_s = expf(1.0f / (float)(deg_s + 1));
  }
  __syncthreads();

  // ---- phase B: survivor-compacted weighted accumulate (rows L2-hot) ----
  constexpr int G = 256 / ZD;           // edge-parallel groups
  const int grp = tid / ZD, ch = tid % ZD;
  float acc = 0.0f;
  for (int base = s; base < e; base += 256){
    int k2 = base + tid;
    if (k2 < e){
      float sv = simcsr[k2];
      if (sv > 0.0f){
        int p = atomicAdd(&cnt2_s, 1);
        wv[p] = expf(sv * inv_s);
        cv[p] = ecol[k2];
      }
    }
    __syncthreads();
    int m = cnt2_s;
    #pragma unroll 4
    for (int t = grp; t < m; t += G)
      acc += wv[t] * zagg[(size_t)cv[t] * ZD + ch];
    __syncthreads();
    if (tid == 0) cnt2_s = 0;
    __syncthreads();
  }

  if constexpr (G == 1){
    out[(size_t)n * 256 + tid] = acc + wself_s * zagg[(size_t)n * 256 + tid];
  } else {
    red[tid] = acc;
    __syncthreads();
    for (int str = 128; str >= ZD; str >>= 1){
      if (tid < str) red[tid] += red[tid + str];
      __syncthreads();
    }
    if (tid < ZD)
      out[(size_t)n * ZD + tid] = red[tid] + wself_s * zagg[(size_t)n * ZD + tid];
  }
}

// ---------------- projection + leaky-ReLU + next-layer invnorm ----------------

template<int D>
__global__ void proj_act_norm(const float* __restrict__ xin, const float* __restrict__ W,
                              float* __restrict__ hout, float* __restrict__ invn, int N){
  // block = 256 threads, 8 nodes per block, 256 outputs (4 heads x 64)
  __shared__ float xs[8][D];
  __shared__ float red[4][8];
  int tid = threadIdx.x;
  int n0 = blockIdx.x * 8;
  for (int i = tid; i < 8 * D; i += 256){
    int nl = i / D, d = i % D;
    int n = n0 + nl;
    xs[nl][d] = (n < N) ? xin[(size_t)n * D + d] : 0.0f;
  }
  __syncthreads();
  int h = tid >> 6, o = tid & 63;
  const float* Wp = W + (size_t)h * D * 64 + o;
  float acc[8];
  #pragma unroll
  for (int i = 0; i < 8; i++) acc[i] = 0.0f;
  for (int d = 0; d < D; d++){
    float w = Wp[(size_t)d * 64];
    #pragma unroll
    for (int i = 0; i < 8; i++) acc[i] += xs[i][d] * w;
  }
  #pragma unroll
  for (int i = 0; i < 8; i++){
    float a = acc[i];
    acc[i] = (a > 0.0f) ? a : 0.01f * a;  // leaky relu
  }
  #pragma unroll
  for (int i = 0; i < 8; i++){
    int n = n0 + i;
    if (n < N) hout[(size_t)n * 256 + tid] = acc[i];
  }
  // fused invnorm of the activated output rows
  int wave = tid >> 6, lane = tid & 63;
  #pragma unroll
  for (int i = 0; i < 8; i++){
    float ss = acc[i] * acc[i];
    for (int off = 32; off; off >>= 1) ss += __shfl_xor(ss, off);
    if (lane == 0) red[wave][i] = ss;
  }
  __syncthreads();
  if (tid < 8){
    int n = n0 + tid;
    if (n < N){
      float t = red[0][tid] + red[1][tid] + red[2][tid] + red[3][tid];
      invn[n] = 1.0f / fmaxf(sqrtf(t), 1e-12f);
    }
  }
}

__global__ void proj16_kernel(const float* __restrict__ x, const float* __restrict__ W,
                              float* __restrict__ z, int N){
  // layer 2: D=256, 16 outputs. 16 nodes x 16 outputs per block
  __shared__ float xs[16][256];   // 16 KB
  __shared__ float wsh[256 * 16]; // 16 KB
  int tid = threadIdx.x;
  int n0 = blockIdx.x * 16;
  for (int i = tid; i < 16 * 256; i += 256){
    int nl = i >> 8, d = i & 255;
    int n = n0 + nl;
    xs[nl][d] = (n < N) ? x[(size_t)n * 256 + d] : 0.0f;
  }
  for (int i = tid; i < 256 * 16; i += 256) wsh[i] = W[i];
  __syncthreads();
  int nl = tid >> 4, o = tid & 15;
  float acc = 0.0f;
  for (int d = 0; d < 256; d++) acc += xs[nl][d] * wsh[d * 16 + o];
  int n = n0 + nl;
  if (n < N) z[(size_t)n * 16 + o] = acc;
}

// ---------------- launch ----------------

extern "C" void kernel_launch(void* const* d_in, const int* in_sizes, int n_in,
                              void* d_out, int out_size, void* d_ws, size_t ws_size,
                              hipStream_t stream){
  const float* x  = (const float*)d_in[0];
  const float* W0 = (const float*)d_in[1];
  const float* W1 = (const float*)d_in[2];
  const float* W2 = (const float*)d_in[3];
  const int*   row = (const int*)d_in[4];
  const int*   col = (const int*)d_in[5];
  const int N = in_sizes[0] / 128;
  const int E = in_sizes[4];
  float* out = (float*)d_out;

  // workspace carve-up (~113 MB)
  float* p = (float*)d_ws;
  float* hbuf   = p; p += (size_t)N * 256;
  float* aggbuf = p; p += (size_t)N * 256;
  float* z2     = p; p += (size_t)N * 16;
  float* simcsr = p; p += E;
  float* invn   = p; p += N;
  int* cnt  = (int*)p;
  int* offs = cnt + N;
  int* cur  = offs + N + 1;
  int* ecol = cur + N;

  // ---- CSR build (row/col static per call) ----
  hipMemsetAsync(cnt, 0, sizeof(int) * N, stream);
  count_kernel<<<cdiv(E, 256), 256, 0, stream>>>(row, cnt, E);
  scan_kernel<<<1, 1024, 0, stream>>>(cnt, offs, N);
  initcur_kernel<<<cdiv(N, 256), 256, 0, stream>>>(offs, cur, N);
  scatter_kernel<<<cdiv(E, 256), 256, 0, stream>>>(row, col, cur, ecol, E);

  // ---- Layer 0: sims on x (D=128), aggregate x, then project W0 + act + norm ----
  invnorm128_kernel<<<cdiv(N, 4), 256, 0, stream>>>(x, invn, N);
  fused_att_agg<128, 128><<<N, 256, 0, stream>>>(x, invn, offs, ecol, simcsr, x, aggbuf, N);
  proj_act_norm<128><<<cdiv(N, 8), 256, 0, stream>>>(aggbuf, W0, hbuf, invn, N);

  // ---- Layer 1: sims on h (D=256), aggregate h, then project W1 + act + norm ----
  fused_att_agg<256, 256><<<N, 256, 0, stream>>>(hbuf, invn, offs, ecol, simcsr, hbuf, aggbuf, N);
  proj_act_norm<256><<<cdiv(N, 8), 256, 0, stream>>>(aggbuf, W1, hbuf, invn, N);

  // ---- Layer 2: z2 = h.W2 (16-d), sims on h, aggregate z2 -> out ----
  proj16_kernel<<<cdiv(N, 16), 256, 0, stream>>>(hbuf, W2, z2, N);
  fused_att_agg<256, 16><<<N, 256, 0, stream>>>(hbuf, invn, offs, ecol, simcsr, z2, out, N);
}

// Round 5
// 1040.781 us; speedup vs baseline: 1.0303x; 1.0303x over previous
//
#include <hip/hip_runtime.h>
#include <math.h>

// GATGuard: 3-layer GAT, cosine-sim attention (thresh 0.1), L1 row norm,
// exp weights, degree self-loop. fp32. N=50000, E=800000, 128->256->256->16.
//
// R5: revert to R3 lane structure (full wave64 per edge for D=256 -> one load
// instruction = one contiguous 1KB row; half-wave per edge for D=128), but
// deepen the phase-A software pipeline to 4 edges in flight per wave.

static inline int cdiv(int a, int b){ return (a + b - 1) / b; }

// ---------------- CSR build (from row[]/col[]) ----------------

__global__ void count_kernel(const int* __restrict__ row, int* __restrict__ cnt, int E){
  int e = blockIdx.x * blockDim.x + threadIdx.x;
  if (e < E) atomicAdd(&cnt[row[e]], 1);
}

__global__ void scan_kernel(const int* __restrict__ cnt, int* __restrict__ offs, int n){
  __shared__ int tmp[1024];
  __shared__ int carry_s;
  int tid = threadIdx.x;
  if (tid == 0) carry_s = 0;
  __syncthreads();
  for (int base = 0; base < n; base += 1024){
    int v = (base + tid < n) ? cnt[base + tid] : 0;
    tmp[tid] = v;
    __syncthreads();
    for (int off = 1; off < 1024; off <<= 1){
      int t = (tid >= off) ? tmp[tid - off] : 0;
      __syncthreads();
      tmp[tid] += t;
      __syncthreads();
    }
    if (base + tid < n) offs[base + tid] = carry_s + tmp[tid] - v;  // exclusive
    __syncthreads();
    if (tid == 0) carry_s += tmp[1023];
    __syncthreads();
  }
  if (tid == 0) offs[n] = carry_s;
}

__global__ void initcur_kernel(const int* __restrict__ offs, int* __restrict__ cur, int n){
  int i = blockIdx.x * blockDim.x + threadIdx.x;
  if (i < n) cur[i] = offs[i];
}

__global__ void scatter_kernel(const int* __restrict__ row, const int* __restrict__ col,
                               int* __restrict__ cur, int* __restrict__ ecol, int E){
  int e = blockIdx.x * blockDim.x + threadIdx.x;
  if (e < E){
    int p = atomicAdd(&cur[row[e]], 1);
    ecol[p] = col[e];
  }
}

// ---------------- layer-0 invnorm (x) ----------------

__global__ void invnorm128_kernel(const float* __restrict__ x, float* __restrict__ invn, int N){
  int n = blockIdx.x * 4 + (threadIdx.x >> 6);
  int lane = threadIdx.x & 63;
  if (n >= N) return;
  float2 a = ((const float2*)(x + (size_t)n * 128))[lane];
  float ss = a.x * a.x + a.y * a.y;
  for (int off = 32; off; off >>= 1) ss += __shfl_xor(ss, off);
  if (lane == 0) invn[n] = 1.0f / fmaxf(sqrtf(ss), 1e-12f);
}

// ---------------- fused attention + input-space aggregation ----------------
// D  = feature dim for similarity (x rows); ZD = dim aggregated; out is N x ZD.
template<int D, int ZD>
__global__ void fused_att_agg(const float* __restrict__ x, const float* __restrict__ invn,
                              const int* __restrict__ offs, const int* __restrict__ ecol,
                              float* __restrict__ simcsr, const float* __restrict__ zagg,
                              float* __restrict__ out, int N){
  __shared__ __align__(16) float xs[D];
  __shared__ float wv[256];
  __shared__ int   cv[256];
  __shared__ float red[256];
  __shared__ float rowsum_s;
  __shared__ int   deg_s;
  __shared__ int   cnt2_s;
  __shared__ float inv_s, wself_s;
  const int n = blockIdx.x;
  const int tid = threadIdx.x;
  const int wave = tid >> 6, lane = tid & 63;
  if (tid == 0){ rowsum_s = 0.0f; deg_s = 0; cnt2_s = 0; }
  const int s = offs[n], e = offs[n + 1];
  const float inr = invn[n];
  for (int i = tid; i < D; i += 256) xs[i] = x[(size_t)n * D + i];
  __syncthreads();

  // ---- phase A: full-wave (D=256) / half-wave (D=128) per edge, 4-deep ----
  if constexpr (D == 256){
    float4 a = ((const float4*)xs)[lane];
    int k = s + wave;
    for (; k + 12 < e; k += 16){
      int c0 = ecol[k], c1 = ecol[k + 4], c2 = ecol[k + 8], c3 = ecol[k + 12];
      float4 b0 = ((const float4*)(x + (size_t)c0 * 256))[lane];
      float4 b1 = ((const float4*)(x + (size_t)c1 * 256))[lane];
      float4 b2 = ((const float4*)(x + (size_t)c2 * 256))[lane];
      float4 b3 = ((const float4*)(x + (size_t)c3 * 256))[lane];
      float d0 = a.x*b0.x + a.y*b0.y + a.z*b0.z + a.w*b0.w;
      float d1 = a.x*b1.x + a.y*b1.y + a.z*b1.z + a.w*b1.w;
      float d2 = a.x*b2.x + a.y*b2.y + a.z*b2.z + a.w*b2.w;
      float d3 = a.x*b3.x + a.y*b3.y + a.z*b3.z + a.w*b3.w;
      #pragma unroll
      for (int off = 32; off; off >>= 1){
        d0 += __shfl_xor(d0, off); d1 += __shfl_xor(d1, off);
        d2 += __shfl_xor(d2, off); d3 += __shfl_xor(d3, off);
      }
      if (lane == 0){
        d0 *= inr * invn[c0];
        d1 *= inr * invn[c1];
        d2 *= inr * invn[c2];
        d3 *= inr * invn[c3];
        if (d0 < 0.1f) d0 = 0.0f;
        if (d1 < 0.1f) d1 = 0.0f;
        if (d2 < 0.1f) d2 = 0.0f;
        if (d3 < 0.1f) d3 = 0.0f;
        simcsr[k] = d0; simcsr[k + 4] = d1; simcsr[k + 8] = d2; simcsr[k + 12] = d3;
        int dg = (d0 != 0.0f) + (d1 != 0.0f) + (d2 != 0.0f) + (d3 != 0.0f);
        if (dg){ atomicAdd(&rowsum_s, d0 + d1 + d2 + d3); atomicAdd(&deg_s, dg); }
      }
    }
    for (; k < e; k += 4){
      int c0 = ecol[k];
      float4 b0 = ((const float4*)(x + (size_t)c0 * 256))[lane];
      float d0 = a.x*b0.x + a.y*b0.y + a.z*b0.z + a.w*b0.w;
      #pragma unroll
      for (int off = 32; off; off >>= 1) d0 += __shfl_xor(d0, off);
      if (lane == 0){
        d0 *= inr * invn[c0];
        if (d0 < 0.1f) d0 = 0.0f;
        simcsr[k] = d0;
        if (d0 != 0.0f){ atomicAdd(&rowsum_s, d0); atomicAdd(&deg_s, 1); }
      }
    }
  } else { // D == 128: half-wave (32 lanes x float4) per edge, 4-deep
    const int half = lane >> 5, hl = lane & 31;
    float4 a = ((const float4*)xs)[hl];
    int k = s + wave * 2 + half;
    for (; k + 24 < e; k += 32){
      int c0 = ecol[k], c1 = ecol[k + 8], c2 = ecol[k + 16], c3 = ecol[k + 24];
      float4 b0 = ((const float4*)(x + (size_t)c0 * 128))[hl];
      float4 b1 = ((const float4*)(x + (size_t)c1 * 128))[hl];
      float4 b2 = ((const float4*)(x + (size_t)c2 * 128))[hl];
      float4 b3 = ((const float4*)(x + (size_t)c3 * 128))[hl];
      float d0 = a.x*b0.x + a.y*b0.y + a.z*b0.z + a.w*b0.w;
      float d1 = a.x*b1.x + a.y*b1.y + a.z*b1.z + a.w*b1.w;
      float d2 = a.x*b2.x + a.y*b2.y + a.z*b2.z + a.w*b2.w;
      float d3 = a.x*b3.x + a.y*b3.y + a.z*b3.z + a.w*b3.w;
      #pragma unroll
      for (int off = 16; off; off >>= 1){
        d0 += __shfl_xor(d0, off); d1 += __shfl_xor(d1, off);
        d2 += __shfl_xor(d2, off); d3 += __shfl_xor(d3, off);
      }
      if (hl == 0){
        d0 *= inr * invn[c0];
        d1 *= inr * invn[c1];
        d2 *= inr * invn[c2];
        d3 *= inr * invn[c3];
        if (d0 < 0.1f) d0 = 0.0f;
        if (d1 < 0.1f) d1 = 0.0f;
        if (d2 < 0.1f) d2 = 0.0f;
        if (d3 < 0.1f) d3 = 0.0f;
        simcsr[k] = d0; simcsr[k + 8] = d1; simcsr[k + 16] = d2; simcsr[k + 24] = d3;
        int dg = (d0 != 0.0f) + (d1 != 0.0f) + (d2 != 0.0f) + (d3 != 0.0f);
        if (dg){ atomicAdd(&rowsum_s, d0 + d1 + d2 + d3); atomicAdd(&deg_s, dg); }
      }
    }
    for (; k < e; k += 8){
      int c0 = ecol[k];
      float4 b0 = ((const float4*)(x + (size_t)c0 * 128))[hl];
      float d0 = a.x*b0.x + a.y*b0.y + a.z*b0.z + a.w*b0.w;
      #pragma unroll
      for (int off = 16; off; off >>= 1) d0 += __shfl_xor(d0, off);
      if (hl == 0){
        d0 *= inr * invn[c0];
        if (d0 < 0.1f) d0 = 0.0f;
        simcsr[k] = d0;
        if (d0 != 0.0f){ atomicAdd(&rowsum_s, d0); atomicAdd(&deg_s, 1); }
      }
    }
  }
  __syncthreads();
  if (tid == 0){
    float rs = rowsum_s;
    inv_s = (rs > 0.0f) ? 1.0f / rs : 0.0f;
    wself_s = expf(1.0f / (float)(deg_s + 1));
  }
  __syncthreads();

  // ---- phase B: survivor-compacted weighted accumulate (rows L2-hot) ----
  constexpr int G = 256 / ZD;           // edge-parallel groups
  const int grp = tid / ZD, ch = tid % ZD;
  float acc = 0.0f;
  for (int base = s; base < e; base += 256){
    int k2 = base + tid;
    if (k2 < e){
      float sv = simcsr[k2];
      if (sv > 0.0f){
        int p = atomicAdd(&cnt2_s, 1);
        wv[p] = expf(sv * inv_s);
        cv[p] = ecol[k2];
      }
    }
    __syncthreads();
    int m = cnt2_s;
    #pragma unroll 4
    for (int t = grp; t < m; t += G)
      acc += wv[t] * zagg[(size_t)cv[t] * ZD + ch];
    __syncthreads();
    if (tid == 0) cnt2_s = 0;
    __syncthreads();
  }

  if constexpr (G == 1){
    out[(size_t)n * 256 + tid] = acc + wself_s * zagg[(size_t)n * 256 + tid];
  } else {
    red[tid] = acc;
    __syncthreads();
    for (int str = 128; str >= ZD; str >>= 1){
      if (tid < str) red[tid] += red[tid + str];
      __syncthreads();
    }
    if (tid < ZD)
      out[(size_t)n * ZD + tid] = red[tid] + wself_s * zagg[(size_t)n * ZD + tid];
  }
}

// ---------------- projection + leaky-ReLU + next-layer invnorm ----------------

template<int D>
__global__ void proj_act_norm(const float* __restrict__ xin, const float* __restrict__ W,
                              float* __restrict__ hout, float* __restrict__ invn, int N){
  // block = 256 threads, 8 nodes per block, 256 outputs (4 heads x 64)
  __shared__ float xs[8][D];
  __shared__ float red[4][8];
  int tid = threadIdx.x;
  int n0 = blockIdx.x * 8;
  for (int i = tid; i < 8 * D; i += 256){
    int nl = i / D, d = i % D;
    int n = n0 + nl;
    xs[nl][d] = (n < N) ? xin[(size_t)n * D + d] : 0.0f;
  }
  __syncthreads();
  int h = tid >> 6, o = tid & 63;
  const float* Wp = W + (size_t)h * D * 64 + o;
  float acc[8];
  #pragma unroll
  for (int i = 0; i < 8; i++) acc[i] = 0.0f;
  for (int d = 0; d < D; d++){
    float w = Wp[(size_t)d * 64];
    #pragma unroll
    for (int i = 0; i < 8; i++) acc[i] += xs[i][d] * w;
  }
  #pragma unroll
  for (int i = 0; i < 8; i++){
    float a = acc[i];
    acc[i] = (a > 0.0f) ? a : 0.01f * a;  // leaky relu
  }
  #pragma unroll
  for (int i = 0; i < 8; i++){
    int n = n0 + i;
    if (n < N) hout[(size_t)n * 256 + tid] = acc[i];
  }
  // fused invnorm of the activated output rows
  int wave = tid >> 6, lane = tid & 63;
  #pragma unroll
  for (int i = 0; i < 8; i++){
    float ss = acc[i] * acc[i];
    for (int off = 32; off; off >>= 1) ss += __shfl_xor(ss, off);
    if (lane == 0) red[wave][i] = ss;
  }
  __syncthreads();
  if (tid < 8){
    int n = n0 + tid;
    if (n < N){
      float t = red[0][tid] + red[1][tid] + red[2][tid] + red[3][tid];
      invn[n] = 1.0f / fmaxf(sqrtf(t), 1e-12f);
    }
  }
}

__global__ void proj16_kernel(const float* __restrict__ x, const float* __restrict__ W,
                              float* __restrict__ z, int N){
  // layer 2: D=256, 16 outputs. 16 nodes x 16 outputs per block
  __shared__ float xs[16][256];   // 16 KB
  __shared__ float wsh[256 * 16]; // 16 KB
  int tid = threadIdx.x;
  int n0 = blockIdx.x * 16;
  for (int i = tid; i < 16 * 256; i += 256){
    int nl = i >> 8, d = i & 255;
    int n = n0 + nl;
    xs[nl][d] = (n < N) ? x[(size_t)n * 256 + d] : 0.0f;
  }
  for (int i = tid; i < 256 * 16; i += 256) wsh[i] = W[i];
  __syncthreads();
  int nl = tid >> 4, o = tid & 15;
  float acc = 0.0f;
  for (int d = 0; d < 256; d++) acc += xs[nl][d] * wsh[d * 16 + o];
  int n = n0 + nl;
  if (n < N) z[(size_t)n * 16 + o] = acc;
}

// ---------------- launch ----------------

extern "C" void kernel_launch(void* const* d_in, const int* in_sizes, int n_in,
                              void* d_out, int out_size, void* d_ws, size_t ws_size,
                              hipStream_t stream){
  const float* x  = (const float*)d_in[0];
  const float* W0 = (const float*)d_in[1];
  const float* W1 = (const float*)d_in[2];
  const float* W2 = (const float*)d_in[3];
  const int*   row = (const int*)d_in[4];
  const int*   col = (const int*)d_in[5];
  const int N = in_sizes[0] / 128;
  const int E = in_sizes[4];
  float* out = (float*)d_out;

  // workspace carve-up (~113 MB)
  float* p = (float*)d_ws;
  float* hbuf   = p; p += (size_t)N * 256;
  float* aggbuf = p; p += (size_t)N * 256;
  float* z2     = p; p += (size_t)N * 16;
  float* simcsr = p; p += E;
  float* invn   = p; p += N;
  int* cnt  = (int*)p;
  int* offs = cnt + N;
  int* cur  = offs + N + 1;
  int* ecol = cur + N;

  // ---- CSR build (row/col static per call) ----
  hipMemsetAsync(cnt, 0, sizeof(int) * N, stream);
  count_kernel<<<cdiv(E, 256), 256, 0, stream>>>(row, cnt, E);
  scan_kernel<<<1, 1024, 0, stream>>>(cnt, offs, N);
  initcur_kernel<<<cdiv(N, 256), 256, 0, stream>>>(offs, cur, N);
  scatter_kernel<<<cdiv(E, 256), 256, 0, stream>>>(row, col, cur, ecol, E);

  // ---- Layer 0: sims on x (D=128), aggregate x, then project W0 + act + norm ----
  invnorm128_kernel<<<cdiv(N, 4), 256, 0, stream>>>(x, invn, N);
  fused_att_agg<128, 128><<<N, 256, 0, stream>>>(x, invn, offs, ecol, simcsr, x, aggbuf, N);
  proj_act_norm<128><<<cdiv(N, 8), 256, 0, stream>>>(aggbuf, W0, hbuf, invn, N);

  // ---- Layer 1: sims on h (D=256), aggregate h, then project W1 + act + norm ----
  fused_att_agg<256, 256><<<N, 256, 0, stream>>>(hbuf, invn, offs, ecol, simcsr, hbuf, aggbuf, N);
  proj_act_norm<256><<<cdiv(N, 8), 256, 0, stream>>>(aggbuf, W1, hbuf, invn, N);

  // ---- Layer 2: z2 = h.W2 (16-d), sims on h, aggregate z2 -> out ----
  proj16_kernel<<<cdiv(N, 16), 256, 0, stream>>>(hbuf, W2, z2, N);
  fused_att_agg<256, 16><<<N, 256, 0, stream>>>(hbuf, invn, offs, ecol, simcsr, z2, out, N);
}

// Round 6
// 932.014 us; speedup vs baseline: 1.1505x; 1.1167x over previous
//
#include <hip/hip_runtime.h>
#include <math.h>

// GATGuard: 3-layer GAT, cosine-sim attention (thresh 0.1), L1 row norm,
// exp weights, degree self-loop. fp32. N=50000, E=800000, 128->256->256->16.
//
// R6: R3 phase-A structure (2-deep, full/half-wave per edge) + LDS edge-row
// cache (phase A stores first 16 gathered rows; phase B reads survivors from
// LDS instead of re-gathering) + fast 3-kernel hierarchical scan for CSR.

static inline int cdiv(int a, int b){ return (a + b - 1) / b; }

// ---------------- CSR build (from row[]/col[]) ----------------

__global__ void count_kernel(const int* __restrict__ row, int* __restrict__ cnt, int E){
  int e = blockIdx.x * blockDim.x + threadIdx.x;
  if (e < E) atomicAdd(&cnt[row[e]], 1);
}

__global__ void scan1_kernel(const int* __restrict__ cnt, int* __restrict__ offs,
                             int* __restrict__ bsum, int n){
  __shared__ int tmp[256];
  int tid = threadIdx.x;
  int g = blockIdx.x * 256 + tid;
  int v = (g < n) ? cnt[g] : 0;
  tmp[tid] = v;
  __syncthreads();
  for (int off = 1; off < 256; off <<= 1){
    int t = (tid >= off) ? tmp[tid - off] : 0;
    __syncthreads();
    tmp[tid] += t;
    __syncthreads();
  }
  if (g < n) offs[g] = tmp[tid] - v;          // in-block exclusive
  if (tid == 255) bsum[blockIdx.x] = tmp[255];
}

__global__ void scan2_kernel(int* __restrict__ bsum, int* __restrict__ offs, int nb, int n){
  __shared__ int tmp[256];
  int tid = threadIdx.x;
  int v = (tid < nb) ? bsum[tid] : 0;
  tmp[tid] = v;
  __syncthreads();
  for (int off = 1; off < 256; off <<= 1){
    int t = (tid >= off) ? tmp[tid - off] : 0;
    __syncthreads();
    tmp[tid] += t;
    __syncthreads();
  }
  if (tid < nb) bsum[tid] = tmp[tid] - v;     // exclusive block offsets
  if (tid == 255) offs[n] = tmp[255];         // grand total = E
}

__global__ void scan3_kernel(int* __restrict__ offs, int* __restrict__ cur,
                             const int* __restrict__ bsum, int n){
  int g = blockIdx.x * 256 + threadIdx.x;
  if (g < n){
    int o = offs[g] + bsum[blockIdx.x];
    offs[g] = o;
    cur[g]  = o;
  }
}

__global__ void scatter_kernel(const int* __restrict__ row, const int* __restrict__ col,
                               int* __restrict__ cur, int* __restrict__ ecol, int E){
  int e = blockIdx.x * blockDim.x + threadIdx.x;
  if (e < E){
    int p = atomicAdd(&cur[row[e]], 1);
    ecol[p] = col[e];
  }
}

// ---------------- layer-0 invnorm (x) ----------------

__global__ void invnorm128_kernel(const float* __restrict__ x, float* __restrict__ invn, int N){
  int n = blockIdx.x * 4 + (threadIdx.x >> 6);
  int lane = threadIdx.x & 63;
  if (n >= N) return;
  float2 a = ((const float2*)(x + (size_t)n * 128))[lane];
  float ss = a.x * a.x + a.y * a.y;
  for (int off = 32; off; off >>= 1) ss += __shfl_xor(ss, off);
  if (lane == 0) invn[n] = 1.0f / fmaxf(sqrtf(ss), 1e-12f);
}

// ---------------- fused attention + input-space aggregation ----------------
// D = sim feature dim; ZD = aggregated dim; CACHE => zagg == x (rows reusable).
template<int D, int ZD, bool CACHE>
__global__ void fused_att_agg(const float* __restrict__ x, const float* __restrict__ invn,
                              const int* __restrict__ offs, const int* __restrict__ ecol,
                              float* __restrict__ simcsr, const float* __restrict__ zagg,
                              float* __restrict__ out, int N){
  constexpr int CE = 16;                       // cached edge rows
  __shared__ __align__(16) float xs[D];
  __shared__ __align__(16) float cache[CACHE ? CE * D : 1];
  __shared__ float wv[256];
  __shared__ int   cv[256];
  __shared__ int   kv[256];
  __shared__ float red[256];
  __shared__ float rowsum_s;
  __shared__ int   deg_s;
  __shared__ int   cnt2_s;
  __shared__ float inv_s, wself_s;
  const int n = blockIdx.x;
  const int tid = threadIdx.x;
  const int wave = tid >> 6, lane = tid & 63;
  if (tid == 0){ rowsum_s = 0.0f; deg_s = 0; cnt2_s = 0; }
  const int s = offs[n], e = offs[n + 1];
  const float inr = invn[n];
  for (int i = tid; i < D; i += 256) xs[i] = x[(size_t)n * D + i];
  __syncthreads();

  // ---- phase A: full-wave (D=256) / half-wave (D=128) per edge, 2-deep ----
  if constexpr (D == 256){
    float4 a = ((const float4*)xs)[lane];
    int k = s + wave;
    for (; k + 4 < e; k += 8){
      int c0 = ecol[k], c1 = ecol[k + 4];
      float4 b0 = ((const float4*)(x + (size_t)c0 * 256))[lane];
      float4 b1 = ((const float4*)(x + (size_t)c1 * 256))[lane];
      if (CACHE && (k - s) < CE)     ((float4*)cache)[(k - s) * 64 + lane] = b0;
      if (CACHE && (k + 4 - s) < CE) ((float4*)cache)[(k + 4 - s) * 64 + lane] = b1;
      float d0 = a.x*b0.x + a.y*b0.y + a.z*b0.z + a.w*b0.w;
      float d1 = a.x*b1.x + a.y*b1.y + a.z*b1.z + a.w*b1.w;
      #pragma unroll
      for (int off = 32; off; off >>= 1){ d0 += __shfl_xor(d0, off); d1 += __shfl_xor(d1, off); }
      if (lane == 0){
        d0 *= inr * invn[c0];
        d1 *= inr * invn[c1];
        if (d0 < 0.1f) d0 = 0.0f;
        if (d1 < 0.1f) d1 = 0.0f;
        simcsr[k] = d0; simcsr[k + 4] = d1;
        int dg = (d0 != 0.0f) + (d1 != 0.0f);
        if (dg){ atomicAdd(&rowsum_s, d0 + d1); atomicAdd(&deg_s, dg); }
      }
    }
    for (; k < e; k += 4){
      int c0 = ecol[k];
      float4 b0 = ((const float4*)(x + (size_t)c0 * 256))[lane];
      if (CACHE && (k - s) < CE) ((float4*)cache)[(k - s) * 64 + lane] = b0;
      float d0 = a.x*b0.x + a.y*b0.y + a.z*b0.z + a.w*b0.w;
      #pragma unroll
      for (int off = 32; off; off >>= 1) d0 += __shfl_xor(d0, off);
      if (lane == 0){
        d0 *= inr * invn[c0];
        if (d0 < 0.1f) d0 = 0.0f;
        simcsr[k] = d0;
        if (d0 != 0.0f){ atomicAdd(&rowsum_s, d0); atomicAdd(&deg_s, 1); }
      }
    }
  } else { // D == 128: half-wave (32 lanes x float4) per edge, 2-deep
    const int half = lane >> 5, hl = lane & 31;
    float4 a = ((const float4*)xs)[hl];
    int k = s + wave * 2 + half;
    for (; k + 8 < e; k += 16){
      int c0 = ecol[k], c1 = ecol[k + 8];
      float4 b0 = ((const float4*)(x + (size_t)c0 * 128))[hl];
      float4 b1 = ((const float4*)(x + (size_t)c1 * 128))[hl];
      if (CACHE && (k - s) < CE)     ((float4*)cache)[(k - s) * 32 + hl] = b0;
      if (CACHE && (k + 8 - s) < CE) ((float4*)cache)[(k + 8 - s) * 32 + hl] = b1;
      float d0 = a.x*b0.x + a.y*b0.y + a.z*b0.z + a.w*b0.w;
      float d1 = a.x*b1.x + a.y*b1.y + a.z*b1.z + a.w*b1.w;
      #pragma unroll
      for (int off = 16; off; off >>= 1){ d0 += __shfl_xor(d0, off); d1 += __shfl_xor(d1, off); }
      if (hl == 0){
        d0 *= inr * invn[c0];
        d1 *= inr * invn[c1];
        if (d0 < 0.1f) d0 = 0.0f;
        if (d1 < 0.1f) d1 = 0.0f;
        simcsr[k] = d0; simcsr[k + 8] = d1;
        int dg = (d0 != 0.0f) + (d1 != 0.0f);
        if (dg){ atomicAdd(&rowsum_s, d0 + d1); atomicAdd(&deg_s, dg); }
      }
    }
    for (; k < e; k += 8){
      int c0 = ecol[k];
      float4 b0 = ((const float4*)(x + (size_t)c0 * 128))[hl];
      if (CACHE && (k - s) < CE) ((float4*)cache)[(k - s) * 32 + hl] = b0;
      float d0 = a.x*b0.x + a.y*b0.y + a.z*b0.z + a.w*b0.w;
      #pragma unroll
      for (int off = 16; off; off >>= 1) d0 += __shfl_xor(d0, off);
      if (hl == 0){
        d0 *= inr * invn[c0];
        if (d0 < 0.1f) d0 = 0.0f;
        simcsr[k] = d0;
        if (d0 != 0.0f){ atomicAdd(&rowsum_s, d0); atomicAdd(&deg_s, 1); }
      }
    }
  }
  __syncthreads();
  if (tid == 0){
    float rs = rowsum_s;
    inv_s = (rs > 0.0f) ? 1.0f / rs : 0.0f;
    wself_s = expf(1.0f / (float)(deg_s + 1));
  }
  __syncthreads();

  // ---- phase B: survivor-compacted weighted accumulate (LDS-cached rows) ----
  constexpr int G = 256 / ZD;           // edge-parallel groups
  const int grp = tid / ZD, ch = tid % ZD;
  float acc = 0.0f;
  for (int base = s; base < e; base += 256){
    int k2 = base + tid;
    if (k2 < e){
      float sv = simcsr[k2];
      if (sv > 0.0f){
        int p = atomicAdd(&cnt2_s, 1);
        wv[p] = expf(sv * inv_s);
        cv[p] = ecol[k2];
        kv[p] = k2 - s;
      }
    }
    __syncthreads();
    int m = cnt2_s;
    for (int t = grp; t < m; t += G){
      float w = wv[t];
      if (CACHE && kv[t] < CE) acc += w * cache[kv[t] * ZD + ch];
      else                     acc += w * zagg[(size_t)cv[t] * ZD + ch];
    }
    __syncthreads();
    if (tid == 0) cnt2_s = 0;
    __syncthreads();
  }

  if constexpr (G == 1){
    float self = CACHE ? xs[tid] : zagg[(size_t)n * 256 + tid];
    out[(size_t)n * 256 + tid] = acc + wself_s * self;
  } else {
    red[tid] = acc;
    __syncthreads();
    for (int str = 128; str >= ZD; str >>= 1){
      if (tid < str) red[tid] += red[tid + str];
      __syncthreads();
    }
    if (tid < ZD){
      float self = CACHE ? xs[tid] : zagg[(size_t)n * ZD + tid];
      out[(size_t)n * ZD + tid] = red[tid] + wself_s * self;
    }
  }
}

// ---------------- projection + leaky-ReLU + next-layer invnorm ----------------

template<int D>
__global__ void proj_act_norm(const float* __restrict__ xin, const float* __restrict__ W,
                              float* __restrict__ hout, float* __restrict__ invn, int N){
  // block = 256 threads, 8 nodes per block, 256 outputs (4 heads x 64)
  __shared__ float xs[8][D];
  __shared__ float red[4][8];
  int tid = threadIdx.x;
  int n0 = blockIdx.x * 8;
  for (int i = tid; i < 8 * D; i += 256){
    int nl = i / D, d = i % D;
    int n = n0 + nl;
    xs[nl][d] = (n < N) ? xin[(size_t)n * D + d] : 0.0f;
  }
  __syncthreads();
  int h = tid >> 6, o = tid & 63;
  const float* Wp = W + (size_t)h * D * 64 + o;
  float acc[8];
  #pragma unroll
  for (int i = 0; i < 8; i++) acc[i] = 0.0f;
  for (int d = 0; d < D; d++){
    float w = Wp[(size_t)d * 64];
    #pragma unroll
    for (int i = 0; i < 8; i++) acc[i] += xs[i][d] * w;
  }
  #pragma unroll
  for (int i = 0; i < 8; i++){
    float a = acc[i];
    acc[i] = (a > 0.0f) ? a : 0.01f * a;  // leaky relu
  }
  #pragma unroll
  for (int i = 0; i < 8; i++){
    int n = n0 + i;
    if (n < N) hout[(size_t)n * 256 + tid] = acc[i];
  }
  // fused invnorm of the activated output rows
  int wave = tid >> 6, lane = tid & 63;
  #pragma unroll
  for (int i = 0; i < 8; i++){
    float ss = acc[i] * acc[i];
    for (int off = 32; off; off >>= 1) ss += __shfl_xor(ss, off);
    if (lane == 0) red[wave][i] = ss;
  }
  __syncthreads();
  if (tid < 8){
    int n = n0 + tid;
    if (n < N){
      float t = red[0][tid] + red[1][tid] + red[2][tid] + red[3][tid];
      invn[n] = 1.0f / fmaxf(sqrtf(t), 1e-12f);
    }
  }
}

__global__ void proj16_kernel(const float* __restrict__ x, const float* __restrict__ W,
                              float* __restrict__ z, int N){
  // layer 2: D=256, 16 outputs. 16 nodes x 16 outputs per block
  __shared__ float xs[16][256];   // 16 KB
  __shared__ float wsh[256 * 16]; // 16 KB
  int tid = threadIdx.x;
  int n0 = blockIdx.x * 16;
  for (int i = tid; i < 16 * 256; i += 256){
    int nl = i >> 8, d = i & 255;
    int n = n0 + nl;
    xs[nl][d] = (n < N) ? x[(size_t)n * 256 + d] : 0.0f;
  }
  for (int i = tid; i < 256 * 16; i += 256) wsh[i] = W[i];
  __syncthreads();
  int nl = tid >> 4, o = tid & 15;
  float acc = 0.0f;
  for (int d = 0; d < 256; d++) acc += xs[nl][d] * wsh[d * 16 + o];
  int n = n0 + nl;
  if (n < N) z[(size_t)n * 16 + o] = acc;
}

// ---------------- launch ----------------

extern "C" void kernel_launch(void* const* d_in, const int* in_sizes, int n_in,
                              void* d_out, int out_size, void* d_ws, size_t ws_size,
                              hipStream_t stream){
  const float* x  = (const float*)d_in[0];
  const float* W0 = (const float*)d_in[1];
  const float* W1 = (const float*)d_in[2];
  const float* W2 = (const float*)d_in[3];
  const int*   row = (const int*)d_in[4];
  const int*   col = (const int*)d_in[5];
  const int N = in_sizes[0] / 128;
  const int E = in_sizes[4];
  float* out = (float*)d_out;

  // workspace carve-up (~113 MB)
  float* p = (float*)d_ws;
  float* hbuf   = p; p += (size_t)N * 256;
  float* aggbuf = p; p += (size_t)N * 256;
  float* z2     = p; p += (size_t)N * 16;
  float* simcsr = p; p += E;
  float* invn   = p; p += N;
  int* cnt  = (int*)p;
  int* offs = cnt + N;
  int* cur  = offs + N + 1;
  int* ecol = cur + N;
  int* bsum = ecol + E;

  const int NB = cdiv(N, 256);

  // ---- CSR build (row/col static per call) ----
  hipMemsetAsync(cnt, 0, sizeof(int) * N, stream);
  count_kernel<<<cdiv(E, 256), 256, 0, stream>>>(row, cnt, E);
  scan1_kernel<<<NB, 256, 0, stream>>>(cnt, offs, bsum, N);
  scan2_kernel<<<1, 256, 0, stream>>>(bsum, offs, NB, N);
  scan3_kernel<<<NB, 256, 0, stream>>>(offs, cur, bsum, N);
  scatter_kernel<<<cdiv(E, 256), 256, 0, stream>>>(row, col, cur, ecol, E);

  // ---- Layer 0: sims on x (D=128), aggregate x, then project W0 + act + norm ----
  invnorm128_kernel<<<cdiv(N, 4), 256, 0, stream>>>(x, invn, N);
  fused_att_agg<128, 128, true><<<N, 256, 0, stream>>>(x, invn, offs, ecol, simcsr, x, aggbuf, N);
  proj_act_norm<128><<<cdiv(N, 8), 256, 0, stream>>>(aggbuf, W0, hbuf, invn, N);

  // ---- Layer 1: sims on h (D=256), aggregate h, then project W1 + act + norm ----
  fused_att_agg<256, 256, true><<<N, 256, 0, stream>>>(hbuf, invn, offs, ecol, simcsr, hbuf, aggbuf, N);
  proj_act_norm<256><<<cdiv(N, 8), 256, 0, stream>>>(aggbuf, W1, hbuf, invn, N);

  // ---- Layer 2: z2 = h.W2 (16-d), sims on h, aggregate z2 -> out ----
  proj16_kernel<<<cdiv(N, 16), 256, 0, stream>>>(hbuf, W2, z2, N);
  fused_att_agg<256, 16, false><<<N, 256, 0, stream>>>(hbuf, invn, offs, ecol, simcsr, z2, out, N);
}

// Round 7
// 874.515 us; speedup vs baseline: 1.2261x; 1.0658x over previous
//
#include <hip/hip_runtime.h>
#include <math.h>

// GATGuard: 3-layer GAT, cosine-sim attention (thresh 0.1), L1 row norm,
// exp weights, degree self-loop. fp32. N=50000, E=800000, 128->256->256->16.
//
// R7: barrier-free wave-per-node fused attention+aggregation. Self row +
// first-R neighbor rows cached in registers; tail survivors compacted into a
// per-wave LDS slice (no syncthreads, no atomics); phase B re-gathers only
// compacted survivors, 2-deep pipelined. Layer 2 aggregates 16-d z2.

static inline int cdiv(int a, int b){ return (a + b - 1) / b; }

// ---------------- small vector helpers ----------------

template<int D> struct VecT;
template<> struct VecT<128>{ using type = float2; };
template<> struct VecT<256>{ using type = float4; };

__device__ inline float vdot(float2 a, float2 b){ return a.x*b.x + a.y*b.y; }
__device__ inline float vdot(float4 a, float4 b){ return a.x*b.x + a.y*b.y + a.z*b.z + a.w*b.w; }
__device__ inline void vfma(float2& acc, float w, float2 b){ acc.x += w*b.x; acc.y += w*b.y; }
__device__ inline void vfma(float4& acc, float w, float4 b){
  acc.x += w*b.x; acc.y += w*b.y; acc.z += w*b.z; acc.w += w*b.w;
}
__device__ inline float2 vscale(float w, float2 a){ return make_float2(w*a.x, w*a.y); }
__device__ inline float4 vscale(float w, float4 a){ return make_float4(w*a.x, w*a.y, w*a.z, w*a.w); }

__device__ inline float wred(float d){
  #pragma unroll
  for (int off = 32; off; off >>= 1) d += __shfl_xor(d, off);
  return d;
}

// ---------------- CSR build (from row[]/col[]) ----------------

__global__ void count_kernel(const int* __restrict__ row, int* __restrict__ cnt, int E){
  int e = blockIdx.x * blockDim.x + threadIdx.x;
  if (e < E) atomicAdd(&cnt[row[e]], 1);
}

__global__ void scan1_kernel(const int* __restrict__ cnt, int* __restrict__ offs,
                             int* __restrict__ bsum, int n){
  __shared__ int tmp[256];
  int tid = threadIdx.x;
  int g = blockIdx.x * 256 + tid;
  int v = (g < n) ? cnt[g] : 0;
  tmp[tid] = v;
  __syncthreads();
  for (int off = 1; off < 256; off <<= 1){
    int t = (tid >= off) ? tmp[tid - off] : 0;
    __syncthreads();
    tmp[tid] += t;
    __syncthreads();
  }
  if (g < n) offs[g] = tmp[tid] - v;          // in-block exclusive
  if (tid == 255) bsum[blockIdx.x] = tmp[255];
}

__global__ void scan2_kernel(int* __restrict__ bsum, int* __restrict__ offs, int nb, int n){
  __shared__ int tmp[256];
  int tid = threadIdx.x;
  int v = (tid < nb) ? bsum[tid] : 0;
  tmp[tid] = v;
  __syncthreads();
  for (int off = 1; off < 256; off <<= 1){
    int t = (tid >= off) ? tmp[tid - off] : 0;
    __syncthreads();
    tmp[tid] += t;
    __syncthreads();
  }
  if (tid < nb) bsum[tid] = tmp[tid] - v;     // exclusive block offsets
  if (tid == 255) offs[n] = tmp[255];         // grand total = E
}

__global__ void scan3_kernel(int* __restrict__ offs, int* __restrict__ cur,
                             const int* __restrict__ bsum, int n){
  int g = blockIdx.x * 256 + threadIdx.x;
  if (g < n){
    int o = offs[g] + bsum[blockIdx.x];
    offs[g] = o;
    cur[g]  = o;
  }
}

__global__ void scatter_kernel(const int* __restrict__ row, const int* __restrict__ col,
                               int* __restrict__ cur, int* __restrict__ ecol, int E){
  int e = blockIdx.x * blockDim.x + threadIdx.x;
  if (e < E){
    int p = atomicAdd(&cur[row[e]], 1);
    ecol[p] = col[e];
  }
}

// ---------------- layer-0 invnorm (x) ----------------

__global__ void invnorm128_kernel(const float* __restrict__ x, float* __restrict__ invn, int N){
  int n = blockIdx.x * 4 + (threadIdx.x >> 6);
  int lane = threadIdx.x & 63;
  if (n >= N) return;
  float2 a = ((const float2*)(x + (size_t)n * 128))[lane];
  float ss = a.x * a.x + a.y * a.y;
  ss = wred(ss);
  if (lane == 0) invn[n] = 1.0f / fmaxf(sqrtf(ss), 1e-12f);
}

// ---------------- barrier-free wave-per-node att + input-space agg ----------------
// D in {128,256}; R = register-cached neighbor rows. out[n] = sum_e w_e x[c_e] + wself x[n].

template<int D, int R>
__global__ void att_agg_wave(const float* __restrict__ x, const float* __restrict__ invn,
                             const int* __restrict__ offs, const int* __restrict__ ecol,
                             float* __restrict__ out, int N){
  using vec = typename VecT<D>::type;
  constexpr int LT = 64;                        // LDS tail-survivor capacity per wave
  __shared__ float tls[4][LT];
  __shared__ int   tlk[4][LT];
  const int wid  = threadIdx.x >> 6;
  const int lane = threadIdx.x & 63;
  const int n = blockIdx.x * 4 + wid;
  if (n >= N) return;
  const int s = offs[n], e = offs[n + 1];
  const float inr = invn[n];
  const vec* xv = (const vec*)x;                // row i = indices [i*64, i*64+64)
  vec a = xv[(size_t)n * 64 + lane];

  vec   br[R];
  float simv[R];
  float rowsum = 0.0f;
  int   deg = 0;

  // ---- phase A, cached slots (static unroll -> rows live in registers) ----
  #pragma unroll
  for (int r = 0; r < R; r++){
    simv[r] = 0.0f;
    if (s + r < e){
      int c = ecol[s + r];
      vec b = xv[(size_t)c * 64 + lane];
      br[r] = b;
      float d = wred(vdot(a, b)) * inr * invn[c];
      if (d < 0.1f) d = 0.0f;
      simv[r] = d;
      rowsum += d;
      deg += (d != 0.0f) ? 1 : 0;
    }
  }

  // ---- phase A, dynamic tail (2-deep), push survivors to per-wave LDS ----
  int tc = 0;
  int kover = e;                                // overflow start (practically never)
  int k = s + R;
  for (; k + 1 < e; k += 2){
    int c0 = ecol[k], c1 = ecol[k + 1];
    vec b0 = xv[(size_t)c0 * 64 + lane];
    vec b1 = xv[(size_t)c1 * 64 + lane];
    float d0 = wred(vdot(a, b0)) * inr * invn[c0];
    float d1 = wred(vdot(a, b1)) * inr * invn[c1];
    if (d0 < 0.1f) d0 = 0.0f;
    if (d1 < 0.1f) d1 = 0.0f;
    rowsum += d0 + d1;
    deg += (d0 != 0.0f) + (d1 != 0.0f);
    if (d0 > 0.0f){
      if (tc < LT){ if (lane == 0){ tls[wid][tc] = d0; tlk[wid][tc] = c0; } tc++; }
      else if (kover > k) kover = k;
    }
    if (d1 > 0.0f){
      if (tc < LT){ if (lane == 0){ tls[wid][tc] = d1; tlk[wid][tc] = c1; } tc++; }
      else if (kover > k + 1) kover = k + 1;
    }
  }
  if (k < e){
    int c0 = ecol[k];
    vec b0 = xv[(size_t)c0 * 64 + lane];
    float d0 = wred(vdot(a, b0)) * inr * invn[c0];
    if (d0 < 0.1f) d0 = 0.0f;
    rowsum += d0;
    deg += (d0 != 0.0f) ? 1 : 0;
    if (d0 > 0.0f){
      if (tc < LT){ if (lane == 0){ tls[wid][tc] = d0; tlk[wid][tc] = c0; } tc++; }
      else if (kover > k) kover = k;
    }
  }

  const float invrs = (rowsum > 0.0f) ? 1.0f / rowsum : 0.0f;
  const float wself = expf(1.0f / (float)(deg + 1));

  // ---- phase B: cached rows from registers, tail survivors re-gathered ----
  vec acc = vscale(wself, a);
  #pragma unroll
  for (int r = 0; r < R; r++){
    if (simv[r] > 0.0f) vfma(acc, expf(simv[r] * invrs), br[r]);
  }
  int j = 0;
  for (; j + 1 < tc; j += 2){
    float w0 = expf(tls[wid][j] * invrs);
    float w1 = expf(tls[wid][j + 1] * invrs);
    int c0 = tlk[wid][j], c1 = tlk[wid][j + 1];
    vec b0 = xv[(size_t)c0 * 64 + lane];
    vec b1 = xv[(size_t)c1 * 64 + lane];
    vfma(acc, w0, b0);
    vfma(acc, w1, b1);
  }
  if (j < tc){
    float w0 = expf(tls[wid][j] * invrs);
    int c0 = tlk[wid][j];
    vec b0 = xv[(size_t)c0 * 64 + lane];
    vfma(acc, w0, b0);
  }
  // overflow path: recompute sims (deterministic, same op order) and accumulate
  for (int k2 = kover; k2 < e; k2++){
    int c = ecol[k2];
    vec b = xv[(size_t)c * 64 + lane];
    float d = wred(vdot(a, b)) * inr * invn[c];
    if (d >= 0.1f) vfma(acc, expf(d * invrs), b);
  }

  ((vec*)out)[(size_t)n * 64 + lane] = acc;
}

// ---------------- layer 2: sims on h (D=256), aggregate z2 (16-d) ----------------

__global__ void att_z16_wave(const float* __restrict__ x, const float* __restrict__ invn,
                             const int* __restrict__ offs, const int* __restrict__ ecol,
                             const float* __restrict__ z2, float* __restrict__ out, int N){
  constexpr int LT = 64;
  __shared__ float tls[4][LT];
  __shared__ int   tlk[4][LT];
  const int wid  = threadIdx.x >> 6;
  const int lane = threadIdx.x & 63;
  const int n = blockIdx.x * 4 + wid;
  if (n >= N) return;
  const int s = offs[n], e = offs[n + 1];
  const float inr = invn[n];
  const float4* xv = (const float4*)x;
  float4 a = xv[(size_t)n * 64 + lane];

  float rowsum = 0.0f;
  int   deg = 0;
  int   tc = 0;
  int   kover = e;
  int k = s;
  for (; k + 1 < e; k += 2){
    int c0 = ecol[k], c1 = ecol[k + 1];
    float4 b0 = xv[(size_t)c0 * 64 + lane];
    float4 b1 = xv[(size_t)c1 * 64 + lane];
    float d0 = wred(vdot(a, b0)) * inr * invn[c0];
    float d1 = wred(vdot(a, b1)) * inr * invn[c1];
    if (d0 < 0.1f) d0 = 0.0f;
    if (d1 < 0.1f) d1 = 0.0f;
    rowsum += d0 + d1;
    deg += (d0 != 0.0f) + (d1 != 0.0f);
    if (d0 > 0.0f){
      if (tc < LT){ if (lane == 0){ tls[wid][tc] = d0; tlk[wid][tc] = c0; } tc++; }
      else if (kover > k) kover = k;
    }
    if (d1 > 0.0f){
      if (tc < LT){ if (lane == 0){ tls[wid][tc] = d1; tlk[wid][tc] = c1; } tc++; }
      else if (kover > k + 1) kover = k + 1;
    }
  }
  if (k < e){
    int c0 = ecol[k];
    float4 b0 = xv[(size_t)c0 * 64 + lane];
    float d0 = wred(vdot(a, b0)) * inr * invn[c0];
    if (d0 < 0.1f) d0 = 0.0f;
    rowsum += d0;
    deg += (d0 != 0.0f) ? 1 : 0;
    if (d0 > 0.0f){
      if (tc < LT){ if (lane == 0){ tls[wid][tc] = d0; tlk[wid][tc] = c0; } tc++; }
      else if (kover > k) kover = k;
    }
  }
  const float invrs = (rowsum > 0.0f) ? 1.0f / rowsum : 0.0f;
  const float wself = expf(1.0f / (float)(deg + 1));

  // phase B: 4 survivor edges in parallel (quarter-wave per edge, 16 channels)
  const int grp = lane >> 4, ch = lane & 15;
  float acc = 0.0f;
  for (int j = grp; j < tc; j += 4){
    float w = expf(tls[wid][j] * invrs);
    int   c = tlk[wid][j];
    acc += w * z2[(size_t)c * 16 + ch];
  }
  for (int k2 = kover; k2 < e; k2++){
    int c = ecol[k2];
    float4 b = xv[(size_t)c * 64 + lane];
    float d = wred(vdot(a, b)) * inr * invn[c];
    if (d >= 0.1f){
      float w = expf(d * invrs);
      if (grp == 0) acc += w * z2[(size_t)c * 16 + ch];
    }
  }
  acc += __shfl_xor(acc, 16);
  acc += __shfl_xor(acc, 32);
  if (lane < 16) out[(size_t)n * 16 + lane] = acc + wself * z2[(size_t)n * 16 + lane];
}

// ---------------- projection + leaky-ReLU + next-layer invnorm ----------------

template<int D>
__global__ void proj_act_norm(const float* __restrict__ xin, const float* __restrict__ W,
                              float* __restrict__ hout, float* __restrict__ invn, int N){
  // block = 256 threads, 8 nodes per block, 256 outputs (4 heads x 64)
  __shared__ float xs[8][D];
  __shared__ float red[4][8];
  int tid = threadIdx.x;
  int n0 = blockIdx.x * 8;
  for (int i = tid; i < 8 * D; i += 256){
    int nl = i / D, d = i % D;
    int n = n0 + nl;
    xs[nl][d] = (n < N) ? xin[(size_t)n * D + d] : 0.0f;
  }
  __syncthreads();
  int h = tid >> 6, o = tid & 63;
  const float* Wp = W + (size_t)h * D * 64 + o;
  float acc[8];
  #pragma unroll
  for (int i = 0; i < 8; i++) acc[i] = 0.0f;
  for (int d = 0; d < D; d++){
    float w = Wp[(size_t)d * 64];
    #pragma unroll
    for (int i = 0; i < 8; i++) acc[i] += xs[i][d] * w;
  }
  #pragma unroll
  for (int i = 0; i < 8; i++){
    float a = acc[i];
    acc[i] = (a > 0.0f) ? a : 0.01f * a;  // leaky relu
  }
  #pragma unroll
  for (int i = 0; i < 8; i++){
    int n = n0 + i;
    if (n < N) hout[(size_t)n * 256 + tid] = acc[i];
  }
  // fused invnorm of the activated output rows
  int wave = tid >> 6, lane = tid & 63;
  #pragma unroll
  for (int i = 0; i < 8; i++){
    float ss = acc[i] * acc[i];
    ss = wred(ss);
    if (lane == 0) red[wave][i] = ss;
  }
  __syncthreads();
  if (tid < 8){
    int n = n0 + tid;
    if (n < N){
      float t = red[0][tid] + red[1][tid] + red[2][tid] + red[3][tid];
      invn[n] = 1.0f / fmaxf(sqrtf(t), 1e-12f);
    }
  }
}

__global__ void proj16_kernel(const float* __restrict__ x, const float* __restrict__ W,
                              float* __restrict__ z, int N){
  // layer 2: D=256, 16 outputs. 16 nodes x 16 outputs per block
  __shared__ float xs[16][256];   // 16 KB
  __shared__ float wsh[256 * 16]; // 16 KB
  int tid = threadIdx.x;
  int n0 = blockIdx.x * 16;
  for (int i = tid; i < 16 * 256; i += 256){
    int nl = i >> 8, d = i & 255;
    int n = n0 + nl;
    xs[nl][d] = (n < N) ? x[(size_t)n * 256 + d] : 0.0f;
  }
  for (int i = tid; i < 256 * 16; i += 256) wsh[i] = W[i];
  __syncthreads();
  int nl = tid >> 4, o = tid & 15;
  float acc = 0.0f;
  for (int d = 0; d < 256; d++) acc += xs[nl][d] * wsh[d * 16 + o];
  int n = n0 + nl;
  if (n < N) z[(size_t)n * 16 + o] = acc;
}

// ---------------- launch ----------------

extern "C" void kernel_launch(void* const* d_in, const int* in_sizes, int n_in,
                              void* d_out, int out_size, void* d_ws, size_t ws_size,
                              hipStream_t stream){
  const float* x  = (const float*)d_in[0];
  const float* W0 = (const float*)d_in[1];
  const float* W1 = (const float*)d_in[2];
  const float* W2 = (const float*)d_in[3];
  const int*   row = (const int*)d_in[4];
  const int*   col = (const int*)d_in[5];
  const int N = in_sizes[0] / 128;
  const int E = in_sizes[4];
  float* out = (float*)d_out;

  // workspace carve-up
  float* p = (float*)d_ws;
  float* hbuf   = p; p += (size_t)N * 256;
  float* aggbuf = p; p += (size_t)N * 256;
  float* z2     = p; p += (size_t)N * 16;
  float* invn   = p; p += N;
  int* cnt  = (int*)p;
  int* offs = cnt + N;
  int* cur  = offs + N + 1;
  int* ecol = cur + N;
  int* bsum = ecol + E;

  const int NB = cdiv(N, 256);

  // ---- CSR build (row/col static per call) ----
  hipMemsetAsync(cnt, 0, sizeof(int) * N, stream);
  count_kernel<<<cdiv(E, 256), 256, 0, stream>>>(row, cnt, E);
  scan1_kernel<<<NB, 256, 0, stream>>>(cnt, offs, bsum, N);
  scan2_kernel<<<1, 256, 0, stream>>>(bsum, offs, NB, N);
  scan3_kernel<<<NB, 256, 0, stream>>>(offs, cur, bsum, N);
  scatter_kernel<<<cdiv(E, 256), 256, 0, stream>>>(row, col, cur, ecol, E);

  // ---- Layer 0: sims on x (D=128), aggregate x, project W0 + act + norm ----
  invnorm128_kernel<<<cdiv(N, 4), 256, 0, stream>>>(x, invn, N);
  att_agg_wave<128, 8><<<cdiv(N, 4), 256, 0, stream>>>(x, invn, offs, ecol, aggbuf, N);
  proj_act_norm<128><<<cdiv(N, 8), 256, 0, stream>>>(aggbuf, W0, hbuf, invn, N);

  // ---- Layer 1: sims on h (D=256), aggregate h, project W1 + act + norm ----
  att_agg_wave<256, 4><<<cdiv(N, 4), 256, 0, stream>>>(hbuf, invn, offs, ecol, aggbuf, N);
  proj_act_norm<256><<<cdiv(N, 8), 256, 0, stream>>>(aggbuf, W1, hbuf, invn, N);

  // ---- Layer 2: z2 = h.W2 (16-d), sims on h, aggregate z2 -> out ----
  proj16_kernel<<<cdiv(N, 16), 256, 0, stream>>>(hbuf, W2, z2, N);
  att_z16_wave<<<cdiv(N, 4), 256, 0, stream>>>(hbuf, invn, offs, ecol, z2, out, N);
}